// Round 7
// baseline (1618.885 us; speedup 1.0000x reference)
//
#include <hip/hip_runtime.h>
#include <math.h>

#define NN 50000
#define TT 9
#define FD 128
#define HD 128

using short8 = __attribute__((ext_vector_type(8))) short;
using f32x4  = __attribute__((ext_vector_type(4))) float;
using f32x2  = __attribute__((ext_vector_type(2))) float;
using half2v = __attribute__((ext_vector_type(2))) _Float16;
typedef unsigned short ushort_t;

__device__ inline unsigned short f2bf(float x) {
  unsigned int u = __float_as_uint(x);
  unsigned int r = (u + 0x7fffu + ((u >> 16) & 1u)) >> 16;
  return (unsigned short)r;
}
__device__ inline float bf2f(unsigned short h) {
  return __uint_as_float(((unsigned int)h) << 16);
}
__device__ inline void split2(float x, unsigned short& h, unsigned short& l) {
  h = f2bf(x);
  l = f2bf(x - bf2f(h));
}
__device__ inline float fast_sigmoid(float x) {
  x = fminf(fmaxf(x, -30.f), 30.f);
  return 1.f / (1.f + __expf(-x));
}
__device__ inline float fast_tanh(float x) {
  x = fminf(fmaxf(x, -15.f), 15.f);
  float e = __expf(2.f * x);
  return (e - 1.f) / (e + 1.f);
}

// ---------------------------------------------------------------------------
// CSR build
// ---------------------------------------------------------------------------
__global__ void k_detect(const unsigned int* __restrict__ e32, int nchk,
                         int* __restrict__ stride_out) {
  __shared__ unsigned int red[256];
  unsigned int acc = 0;
  for (int i = threadIdx.x; i < nchk; i += 256) acc |= e32[2 * i + 1];
  red[threadIdx.x] = acc;
  __syncthreads();
  for (int s = 128; s > 0; s >>= 1) {
    if ((int)threadIdx.x < s) red[threadIdx.x] |= red[threadIdx.x + s];
    __syncthreads();
  }
  if (threadIdx.x == 0) stride_out[0] = (red[0] == 0u) ? 2 : 1;
}

__global__ void k_count(const unsigned int* __restrict__ e32, int E,
                        const int* __restrict__ stridep, int* __restrict__ cnt) {
  int e = blockIdx.x * 256 + threadIdx.x;
  if (e >= E) return;
  int st = stridep[0];
  int d = (int)e32[(size_t)(E + e) * st];
  atomicAdd(&cnt[d], 1);
}

__global__ void k_dinv(const int* __restrict__ cnt, float* __restrict__ dinv, int N) {
  int n = blockIdx.x * 256 + threadIdx.x;
  if (n < N) dinv[n] = rsqrtf((float)(cnt[n] + 1));
}

__global__ void k_scan(const int* __restrict__ cnt, int* __restrict__ rowp, int N) {
  __shared__ int buf[1024];
  __shared__ int carry_s;
  if (threadIdx.x == 0) carry_s = 0;
  __syncthreads();
  for (int base = 0; base < N; base += 1024) {
    int i = base + threadIdx.x;
    int v = (i < N) ? cnt[i] : 0;
    buf[threadIdx.x] = v;
    __syncthreads();
    for (int off = 1; off < 1024; off <<= 1) {
      int t = ((int)threadIdx.x >= off) ? buf[threadIdx.x - off] : 0;
      __syncthreads();
      buf[threadIdx.x] += t;
      __syncthreads();
    }
    int incl = buf[threadIdx.x];
    int carry = carry_s;
    if (i < N) rowp[i] = carry + incl - v;
    __syncthreads();
    if (threadIdx.x == 1023) carry_s = carry + incl;
    __syncthreads();
  }
  if (threadIdx.x == 0) rowp[N] = carry_s;
}

__global__ void k_scatter(const unsigned int* __restrict__ e32, int E,
                          const int* __restrict__ stridep, const int* __restrict__ rowp,
                          int* __restrict__ fill, int* __restrict__ col) {
  int e = blockIdx.x * 256 + threadIdx.x;
  if (e >= E) return;
  int st = stridep[0];
  int s = (int)e32[(size_t)e * st];
  int d = (int)e32[(size_t)(E + e) * st];
  int pos = rowp[d] + atomicAdd(&fill[d], 1);
  col[pos] = s;
}

// ---------------------------------------------------------------------------
// k_prep: xs16[t][n][128] = fp16( x_seq[t][n][d] * dinv[n] )
// ---------------------------------------------------------------------------
__global__ __launch_bounds__(256) void k_prep(const float* __restrict__ x,
                                              const float* __restrict__ dinv,
                                              _Float16* __restrict__ xs) {
  int lane = threadIdx.x & 63;
  int n = blockIdx.x * 4 + (threadIdx.x >> 6);
  int t = blockIdx.y;
  float dn = dinv[n];
  f32x2 v = __builtin_nontemporal_load(
      (const f32x2*)(x + ((size_t)t * NN + n) * 128 + lane * 2));
  half2v r;
  r.x = (_Float16)(v.x * dn);
  r.y = (_Float16)(v.y * dn);
  *(half2v*)(xs + ((size_t)t * NN + n) * 128 + lane * 2) = r;
}

// ---------------------------------------------------------------------------
// Weight packs: k-chunked [kchunk][row][8] so MFMA frag loads are coalesced.
// ---------------------------------------------------------------------------
__global__ void k_packw(const float* __restrict__ Wih, const float* __restrict__ Whh,
                        const float* __restrict__ bih, const float* __restrict__ bhh,
                        ushort_t* __restrict__ Wh_, ushort_t* __restrict__ Wl_,
                        float* __restrict__ bsum) {
  int r = blockIdx.x;   // 0..511 original gate-row
  int k = threadIdx.x;  // 0..255
  int ri = (r & 127) * 4 + (r >> 7);
  float v = (k < 128) ? Wih[(size_t)r * 128 + k] : Whh[(size_t)r * 128 + (k - 128)];
  unsigned short h, l;
  split2(v, h, l);
  size_t o = ((size_t)(k >> 3) * 512 + ri) * 8 + (k & 7);
  Wh_[o] = h;
  Wl_[o] = l;
  if (k == 0) bsum[ri] = bih[r] + bhh[r];
}

__global__ void k_packg(const float* __restrict__ Wg, ushort_t* __restrict__ Bh_,
                        ushort_t* __restrict__ Bl_) {
  int h = blockIdx.x, k = threadIdx.x;  // 128 x 128
  unsigned short hh, ll;
  split2(Wg[(size_t)k * 128 + h], hh, ll);
  size_t o = ((size_t)(k >> 3) * 128 + h) * 8 + (k & 7);
  Bh_[o] = hh;
  Bl_[o] = ll;
}

// ---------------------------------------------------------------------------
// k_agg: one wave per node, ALL 9 timesteps per edge visit (xs16 = 115MB,
// L3-resident). 2-edge x 9-t unroll -> 18 independent gathers in flight.
// col read once per node. Output split-bf16 k-chunked via LDS transpose,
// nontemporal stores (don't evict xs from L3).
// ---------------------------------------------------------------------------
__global__ __launch_bounds__(256) void k_agg(const _Float16* __restrict__ xs,
                                             const float* __restrict__ dinv,
                                             const int* __restrict__ rowp,
                                             const int* __restrict__ col,
                                             ushort_t* __restrict__ agg_h,
                                             ushort_t* __restrict__ agg_l) {
  __shared__ unsigned int pk[4][9][130];
  int lane = threadIdx.x & 63;
  int wv = threadIdx.x >> 6;
  int n = blockIdx.x * 4 + wv;
  float dn = dinv[n];
  float ax[9], ay[9];
  {
    const _Float16* xrow = xs + (size_t)n * 128 + lane * 2;
#pragma unroll
    for (int t = 0; t < 9; ++t) {
      half2v sv = *(const half2v*)(xrow + (size_t)t * NN * 128);
      ax[t] = (float)sv.x;  // self-loop (xs pre-scaled by dinv)
      ay[t] = (float)sv.y;
    }
  }
  int beg = rowp[n], end = rowp[n + 1];
  for (int base = beg; base < end; base += 64) {
    int m = end - base;
    if (m > 64) m = 64;
    int sl = (lane < m) ? col[base + lane] : 0;
    int j = 0;
    for (; j + 2 <= m; j += 2) {
      int s0 = __shfl(sl, j), s1 = __shfl(sl, j + 1);
      const _Float16* r0 = xs + (size_t)s0 * 128 + lane * 2;
      const _Float16* r1 = xs + (size_t)s1 * 128 + lane * 2;
      half2v g0[9], g1[9];
#pragma unroll
      for (int t = 0; t < 9; ++t) g0[t] = *(const half2v*)(r0 + (size_t)t * NN * 128);
#pragma unroll
      for (int t = 0; t < 9; ++t) g1[t] = *(const half2v*)(r1 + (size_t)t * NN * 128);
#pragma unroll
      for (int t = 0; t < 9; ++t) {
        ax[t] += (float)g0[t].x + (float)g1[t].x;
        ay[t] += (float)g0[t].y + (float)g1[t].y;
      }
    }
    if (j < m) {
      int s0 = __shfl(sl, j);
      const _Float16* r0 = xs + (size_t)s0 * 128 + lane * 2;
      half2v g0[9];
#pragma unroll
      for (int t = 0; t < 9; ++t) g0[t] = *(const half2v*)(r0 + (size_t)t * NN * 128);
#pragma unroll
      for (int t = 0; t < 9; ++t) {
        ax[t] += (float)g0[t].x;
        ay[t] += (float)g0[t].y;
      }
    }
  }
#pragma unroll
  for (int t = 0; t < 9; ++t) {
    unsigned short hx, lx, hy, ly;
    split2(ax[t] * dn, hx, lx);
    split2(ay[t] * dn, hy, ly);
    pk[wv][t][lane * 2] = ((unsigned int)hx << 16) | lx;
    pk[wv][t][lane * 2 + 1] = ((unsigned int)hy << 16) | ly;
  }
  __syncthreads();
  // writeback: unit u -> (g = u&3, chunk = (u>>2)&15, t = u>>6); 4 nodes of a
  // (chunk,t) are written by 4 consecutive lanes -> 64B-contiguous stores.
  int n0 = blockIdx.x * 4;
  for (int u = threadIdx.x; u < 576; u += 256) {
    int g = u & 3, chunk = (u >> 2) & 15, t = u >> 6;
    const unsigned int* src = &pk[g][t][chunk * 8];
    unsigned int p[8];
#pragma unroll
    for (int e = 0; e < 8; ++e) p[e] = src[e];
    union { unsigned int u4[4]; short8 s; } rh, rl;
#pragma unroll
    for (int k2 = 0; k2 < 4; ++k2) {
      rh.u4[k2] = __builtin_amdgcn_perm(p[2 * k2 + 1], p[2 * k2], 0x07060302u);
      rl.u4[k2] = __builtin_amdgcn_perm(p[2 * k2 + 1], p[2 * k2], 0x05040100u);
    }
    size_t o = ((size_t)(chunk * 9 + t) * NN + n0 + g) * 8;
    __builtin_nontemporal_store(rh.s, (short8*)(agg_h + o));
    __builtin_nontemporal_store(rl.s, (short8*)(agg_l + o));
  }
}

// ---------------------------------------------------------------------------
// k_fused: GCN GEMM + full T=9 LSTM + out-projection in one kernel.
// 512 thr (8 waves) x 48 nodes. ldsE/ldsH as SEPARATE hi/lo ushort planes so
// Phase-G B-frags are direct ds_read_b128 (no v_perm unpacking).
// ---------------------------------------------------------------------------
#define BN 48
#define LST 136  // row stride (ushorts): 16B-aligned rows, 2-way-max bank alias
__global__ __launch_bounds__(512, 4) void k_fused(
    const ushort_t* __restrict__ Ah_, const ushort_t* __restrict__ Al_,
    const ushort_t* __restrict__ Gh_, const ushort_t* __restrict__ Gl_,
    const float* __restrict__ bg, const ushort_t* __restrict__ Wh_,
    const ushort_t* __restrict__ Wl_, const float* __restrict__ bsum,
    const float* __restrict__ Wfc, const float* __restrict__ bfc,
    float* __restrict__ out) {
  __shared__ ushort_t ldsEh[BN * LST];
  __shared__ ushort_t ldsEl[BN * LST];
  __shared__ ushort_t ldsHh[BN * LST];
  __shared__ ushort_t ldsHl[BN * LST];
  __shared__ float obuf[8][BN];
  int tid = threadIdx.x;
  int w = tid >> 6, lane = tid & 63, q = lane >> 4, cl = lane & 15;
  int n0 = blockIdx.x * BN;
  const short8 zz = {0, 0, 0, 0, 0, 0, 0, 0};
  float cst[4][3] = {};
  float bfv = bfc[0];
#pragma unroll 1
  for (int t = 0; t < TT; ++t) {
    // ---- Phase E: emb^T = Wgt @ agg^T ----
    {
      f32x4 acce[3] = {};
#pragma unroll 1
      for (int ks = 0; ks < 4; ++ks) {
        int chunk = ks * 4 + q;
        size_t ao = ((size_t)chunk * 128 + w * 16 + cl) * 8;
        short8 gah = *(const short8*)(Gh_ + ao);
        short8 gal = *(const short8*)(Gl_ + ao);
#pragma unroll
        for (int ct = 0; ct < 3; ++ct) {
          int node = n0 + ct * 16 + cl;
          short8 bh = zz, bl = zz;
          if (node < NN) {
            size_t o = ((size_t)(chunk * 9 + t) * NN + node) * 8;
            bh = __builtin_nontemporal_load((const short8*)(Ah_ + o));
            bl = __builtin_nontemporal_load((const short8*)(Al_ + o));
          }
          acce[ct] = __builtin_amdgcn_mfma_f32_16x16x32_bf16(gah, bh, acce[ct], 0, 0, 0);
          acce[ct] = __builtin_amdgcn_mfma_f32_16x16x32_bf16(gah, bl, acce[ct], 0, 0, 0);
          acce[ct] = __builtin_amdgcn_mfma_f32_16x16x32_bf16(gal, bh, acce[ct], 0, 0, 0);
        }
      }
#pragma unroll
      for (int ct = 0; ct < 3; ++ct) {
#pragma unroll
        for (int j = 0; j < 4; ++j) {
          int hid = w * 16 + q * 4 + j;
          float v = acce[ct][j] + bg[hid];
          v = v > 0.f ? v : 0.f;
          unsigned short hh, hl;
          split2(v, hh, hl);
          int ro = (ct * 16 + cl) * LST + hid;
          ldsEh[ro] = hh;
          ldsEl[ro] = hl;
        }
      }
    }
    __syncthreads();  // BAR1: ldsE(t) ready
    // ---- Phase G: gates^T = Wpk @ [emb|h]^T ----
    f32x4 acc[4][3] = {};
    int ksmax = (t == 0) ? 4 : 8;
#pragma unroll 1
    for (int ks = 0; ks < ksmax; ++ks) {
      int chunk = ks * 4 + q;
      const ushort_t* Bh = (ks < 4) ? ldsEh : ldsHh;
      const ushort_t* Bl = (ks < 4) ? ldsEl : ldsHl;
      int kk = (ks & 3) * 32 + q * 8;
      short8 bh[3], bl[3];
#pragma unroll
      for (int ct = 0; ct < 3; ++ct) {
        int ro = (ct * 16 + cl) * LST + kk;
        bh[ct] = *(const short8*)(Bh + ro);
        bl[ct] = *(const short8*)(Bl + ro);
      }
#pragma unroll
      for (int rt = 0; rt < 4; ++rt) {
        size_t ao = ((size_t)chunk * 512 + w * 64 + rt * 16 + cl) * 8;
        short8 ah = *(const short8*)(Wh_ + ao);
        short8 al = *(const short8*)(Wl_ + ao);
#pragma unroll
        for (int ct = 0; ct < 3; ++ct) {
          acc[rt][ct] = __builtin_amdgcn_mfma_f32_16x16x32_bf16(ah, bh[ct], acc[rt][ct], 0, 0, 0);
          acc[rt][ct] = __builtin_amdgcn_mfma_f32_16x16x32_bf16(ah, bl[ct], acc[rt][ct], 0, 0, 0);
          acc[rt][ct] = __builtin_amdgcn_mfma_f32_16x16x32_bf16(al, bh[ct], acc[rt][ct], 0, 0, 0);
        }
      }
    }
    __syncthreads();  // BAR2: all ldsE/ldsH reads done before h(t) writes
    // ---- Epilogue ----
    float op[3] = {0.f, 0.f, 0.f};
#pragma unroll
    for (int rt = 0; rt < 4; ++rt) {
      int jl = w * 16 + rt * 4 + q;
      float4 bs = *(const float4*)(bsum + jl * 4);
      float wf = Wfc[jl];
#pragma unroll
      for (int ct = 0; ct < 3; ++ct) {
        float gi = acc[rt][ct][0] + bs.x;
        float gf = acc[rt][ct][1] + bs.y;
        float gg = acc[rt][ct][2] + bs.z;
        float go = acc[rt][ct][3] + bs.w;
        float ig = fast_sigmoid(gi), fg = fast_sigmoid(gf), og = fast_sigmoid(go);
        float gt = fast_tanh(gg);
        float cn = fg * cst[rt][ct] + ig * gt;
        cst[rt][ct] = cn;
        float hn = og * fast_tanh(cn);
        op[ct] += hn * wf;
        unsigned short hh, hl;
        split2(hn, hh, hl);
        int ro = (ct * 16 + cl) * LST + jl;
        ldsHh[ro] = hh;
        ldsHl[ro] = hl;
      }
    }
#pragma unroll
    for (int ct = 0; ct < 3; ++ct) {
      op[ct] += __shfl_xor(op[ct], 16);
      op[ct] += __shfl_xor(op[ct], 32);
    }
    if (q == 0) {
#pragma unroll
      for (int ct = 0; ct < 3; ++ct) obuf[w][ct * 16 + cl] = op[ct];
    }
    __syncthreads();  // BAR3: h(t) + obuf visible
    if (tid < BN) {
      int node = n0 + tid;
      if (node < NN) {
        float v = bfv;
#pragma unroll
        for (int ww = 0; ww < 8; ++ww) v += obuf[ww][tid];
        out[(size_t)node * TT + t] = v;
      }
    }
  }
}

// ---------------------------------------------------------------------------
static inline size_t alignup(size_t x) { return (x + 511) & ~(size_t)511; }

extern "C" void kernel_launch(void* const* d_in, const int* in_sizes, int n_in,
                              void* d_out, int out_size, void* d_ws, size_t ws_size,
                              hipStream_t stream) {
  const float* x_seq = (const float*)d_in[0];
  const unsigned int* e32 = (const unsigned int*)d_in[1];
  const float* W_gcn = (const float*)d_in[2];
  const float* b_gcn = (const float*)d_in[3];
  const float* W_ih = (const float*)d_in[4];
  const float* W_hh = (const float*)d_in[5];
  const float* b_ih = (const float*)d_in[6];
  const float* b_hh = (const float*)d_in[7];
  const float* W_fc = (const float*)d_in[8];
  const float* b_fc = (const float*)d_in[9];
  float* out = (float*)d_out;

  const int N = NN;
  const int E = in_sizes[1] / 2;

  char* p = (char*)d_ws;
  int* stridep = (int*)p;                    p += 512;
  int* cnt = (int*)p;                        p += alignup((size_t)N * 4);
  int* rowp = (int*)p;                       p += alignup((size_t)(N + 1) * 4);
  int* col = (int*)p;                        p += alignup((size_t)E * 4);
  float* dinv = (float*)p;                   p += alignup((size_t)N * 4);
  _Float16* xs16 = (_Float16*)p;             p += alignup((size_t)9 * N * 128 * 2);
  ushort_t* agg_h = (ushort_t*)p;            p += alignup((size_t)16 * 9 * N * 8 * 2);
  ushort_t* agg_l = (ushort_t*)p;            p += alignup((size_t)16 * 9 * N * 8 * 2);
  ushort_t* wpkh = (ushort_t*)p;             p += alignup((size_t)32 * 512 * 8 * 2);
  ushort_t* wpkl = (ushort_t*)p;             p += alignup((size_t)32 * 512 * 8 * 2);
  ushort_t* wgth = (ushort_t*)p;             p += alignup((size_t)16 * 128 * 8 * 2);
  ushort_t* wgtl = (ushort_t*)p;             p += alignup((size_t)16 * 128 * 8 * 2);
  float* bsum = (float*)p;                   p += alignup((size_t)512 * 4);

  hipMemsetAsync(cnt, 0, (size_t)N * 4, stream);

  int nchk = E < 8192 ? E : 8192;
  k_detect<<<1, 256, 0, stream>>>(e32, nchk, stridep);
  k_count<<<(E + 255) / 256, 256, 0, stream>>>(e32, E, stridep, cnt);
  k_dinv<<<(N + 255) / 256, 256, 0, stream>>>(cnt, dinv, N);
  k_scan<<<1, 1024, 0, stream>>>(cnt, rowp, N);
  hipMemsetAsync(cnt, 0, (size_t)N * 4, stream);  // reuse as fill
  k_scatter<<<(E + 255) / 256, 256, 0, stream>>>(e32, E, stridep, rowp, cnt, col);
  k_prep<<<dim3(N / 4, 9), 256, 0, stream>>>(x_seq, dinv, xs16);
  k_packw<<<512, 256, 0, stream>>>(W_ih, W_hh, b_ih, b_hh, wpkh, wpkl, bsum);
  k_packg<<<128, 128, 0, stream>>>(W_gcn, wgth, wgtl);

  k_agg<<<N / 4, 256, 0, stream>>>(xs16, dinv, rowp, col, agg_h, agg_l);
  k_fused<<<(N + BN - 1) / BN, 512, 0, stream>>>(agg_h, agg_l, wgth, wgtl, b_gcn,
                                                 wpkh, wpkl, bsum, W_fc, b_fc, out);
}